// Round 4
// baseline (21270.094 us; speedup 1.0000x reference)
//
#include <hip/hip_runtime.h>
#include <hip/hip_fp16.h>
#include <math.h>

#define B 8
#define M 256
#define D 65536
#define NCH 512   // D / 128 column-chunks

static constexpr float ALPHA = 0.5f;
static constexpr int N_ITERS = 50;
static constexpr int N_POWER = 10;

typedef _Float16 f16x8 __attribute__((ext_vector_type(8)));
typedef float f32x4 __attribute__((ext_vector_type(4)));

// ---------------------------------------------------------------------------
// Tile-major fp16 layout: Aht[b][ch][m][dlo], ch = d>>7, dlo = d&127.
// ---------------------------------------------------------------------------

// K0: convert A fp32 -> fp16 tile-major. i enumerates OUTPUT uint4s so the
// write stream is perfectly sequential; reads are 512B contiguous segments
// (16 lanes x 32B within one source row).
__global__ __launch_bounds__(256) void k_conv(const float* __restrict__ A,
                                              __half* __restrict__ Aht) {
    const size_t n8 = (size_t)B * M * D / 8;  // 16,777,216 output uint4s
    size_t stride = (size_t)gridDim.x * 256;
    for (size_t i = (size_t)blockIdx.x * 256 + threadIdx.x; i < n8; i += stride) {
        size_t dlo8 = i & 15;
        size_t m  = (i >> 4) & (M - 1);
        size_t ch = (i >> 12) & (NCH - 1);
        size_t b  = i >> 21;
        size_t in8 = (b << 21) | (m << 13) | (ch << 4) | dlo8;
        float4 f0 = ((const float4*)A)[2 * in8];
        float4 f1 = ((const float4*)A)[2 * in8 + 1];
        union { uint4 u; __half2 h[4]; } o;
        o.h[0] = __floats2half2_rn(f0.x, f0.y);
        o.h[1] = __floats2half2_rn(f0.z, f0.w);
        o.h[2] = __floats2half2_rn(f1.x, f1.y);
        o.h[3] = __floats2half2_rn(f1.z, f1.w);
        ((uint4*)Aht)[i] = o.u;
    }
}

// ---------------------------------------------------------------------------
// K1a: per-(b,ch) partials of y[b,m] = dot(Ah[m,:], x) and rowsum(Ah[m,:]).
// ---------------------------------------------------------------------------
__global__ __launch_bounds__(256) void k_ypart(const __half* __restrict__ Aht,
                                               const float* __restrict__ x,
                                               float* __restrict__ ypart,
                                               float* __restrict__ upart) {
    int cid = blockIdx.x;
    int b = cid >> 9;
    int ch = cid & (NCH - 1);
    int t = threadIdx.x;
    int dj = t & 15;
    int mi = t >> 4;

    __shared__ float xs[128];
    __shared__ float sredY[M];
    __shared__ float sredU[M];
    if (t < 32)
        ((float4*)xs)[t] = ((const float4*)(x + (size_t)b * D + ch * 128))[t];
    __syncthreads();

    float zr[8];
    {
        float4 z0 = *(const float4*)&xs[dj * 8];
        float4 z1 = *(const float4*)&xs[dj * 8 + 4];
        zr[0] = z0.x; zr[1] = z0.y; zr[2] = z0.z; zr[3] = z0.w;
        zr[4] = z1.x; zr[5] = z1.y; zr[6] = z1.z; zr[7] = z1.w;
    }

    const __half* Ap = Aht + (((size_t)b * NCH + ch) * M + mi) * 128 + dj * 8;
#pragma unroll
    for (int s = 0; s < 16; ++s) {
        uint4 a = *(const uint4*)(Ap + (size_t)(s * 16) * 128);
        const __half2* hp = (const __half2*)&a;
        float2 f0 = __half22float2(hp[0]);
        float2 f1 = __half22float2(hp[1]);
        float2 f2 = __half22float2(hp[2]);
        float2 f3 = __half22float2(hp[3]);
        float p = f0.x * zr[0] + f0.y * zr[1] + f1.x * zr[2] + f1.y * zr[3] +
                  f2.x * zr[4] + f2.y * zr[5] + f3.x * zr[6] + f3.y * zr[7];
        float q = f0.x + f0.y + f1.x + f1.y + f2.x + f2.y + f3.x + f3.y;
        p += __shfl_xor(p, 1, 64); q += __shfl_xor(q, 1, 64);
        p += __shfl_xor(p, 2, 64); q += __shfl_xor(q, 2, 64);
        p += __shfl_xor(p, 4, 64); q += __shfl_xor(q, 4, 64);
        p += __shfl_xor(p, 8, 64); q += __shfl_xor(q, 8, 64);
        if (dj == 0) { sredY[s * 16 + mi] = p; sredU[s * 16 + mi] = q; }
    }
    __syncthreads();
    ypart[((size_t)b * NCH + ch) * M + t] = sredY[t];
    upart[((size_t)b * NCH + ch) * M + t] = sredU[t];
}

// K1b: y[b,m] = sum_ch ypart; u[b,m] = sum_ch upart / 256
__global__ __launch_bounds__(256) void k_yred(const float* __restrict__ ypart,
                                              const float* __restrict__ upart,
                                              float* __restrict__ y,
                                              float* __restrict__ u) {
    int blk = blockIdx.x;          // 64 = B * 8
    int b = blk >> 3;
    int mg = blk & 7;
    int t = threadIdx.x;
    int tm = t & 31;
    int cg = t >> 5;
    int m = mg * 32 + tm;
    const float* yp = ypart + (size_t)b * NCH * M + m;
    const float* up = upart + (size_t)b * NCH * M + m;
    float sy = 0.f, su = 0.f;
#pragma unroll 8
    for (int ch = cg; ch < NCH; ch += 8) {
        sy += yp[(size_t)ch * M];
        su += up[(size_t)ch * M];
    }
    __shared__ float redY[8][32], redU[8][32];
    redY[cg][tm] = sy; redU[cg][tm] = su;
    __syncthreads();
    if (t < 32) {
        float vy = 0.f, vu = 0.f;
#pragma unroll
        for (int g = 0; g < 8; ++g) { vy += redY[g][t]; vu += redU[g][t]; }
        int bm = b * M + mg * 32 + t;
        y[bm] = vy;
        u[bm] = vu * 0.00390625f;
    }
}

// ---------------------------------------------------------------------------
// K2 (MFMA): Gram G[b] = Ah[b] * Ah[b]^T using v_mfma_f32_16x16x32_f16.
// ---------------------------------------------------------------------------
__global__ __launch_bounds__(256) void k_gram_mfma(const __half* __restrict__ Aht,
                                                   float* __restrict__ G) {
    int bx = blockIdx.x;
    int ch2 = bx & 31;             // 32 K-chunks of 2048
    int p  = (bx >> 5) % 3;        // pair: (0,0) (0,128) (128,128)
    int b  = bx / 96;
    const int PI[3] = {0, 0, 128};
    const int PJ[3] = {0, 128, 128};
    int ti = PI[p], tj = PJ[p];
    int k0 = ch2 * 2048;

    __shared__ __half As[128 * 32];
    __shared__ __half Bs[128 * 32];

    int t = threadIdx.x;
    int w = t >> 6, lane = t & 63;
    int wr = w >> 1, wc = w & 1;

    int srow = w * 32 + (lane >> 2);
    int scol = (lane & 3) * 8;

    f32x4 acc[4][4];
#pragma unroll
    for (int i = 0; i < 4; ++i)
#pragma unroll
        for (int j = 0; j < 4; ++j)
            acc[i][j] = (f32x4){0.f, 0.f, 0.f, 0.f};

    int frow = lane & 15;
    int koff = (lane >> 4) * 8;

    const size_t bbase = (size_t)b * NCH;
    for (int ks = 0; ks < 2048; ks += 32) {
        int d = k0 + ks;
        size_t chb = bbase + (d >> 7);
        int dlo = d & 127;
        __syncthreads();
        {
            const __half* ga0 = Aht + (chb * M + (ti + srow)) * 128 + dlo + scol;
            const __half* ga1 = ga0 + 16 * 128;
            const __half* gb0 = Aht + (chb * M + (tj + srow)) * 128 + dlo + scol;
            const __half* gb1 = gb0 + 16 * 128;
            __builtin_amdgcn_global_load_lds(
                (const __attribute__((address_space(1))) void*)ga0,
                (__attribute__((address_space(3))) void*)&As[(w * 32) * 32], 16, 0, 0);
            __builtin_amdgcn_global_load_lds(
                (const __attribute__((address_space(1))) void*)ga1,
                (__attribute__((address_space(3))) void*)&As[(w * 32 + 16) * 32], 16, 0, 0);
            __builtin_amdgcn_global_load_lds(
                (const __attribute__((address_space(1))) void*)gb0,
                (__attribute__((address_space(3))) void*)&Bs[(w * 32) * 32], 16, 0, 0);
            __builtin_amdgcn_global_load_lds(
                (const __attribute__((address_space(1))) void*)gb1,
                (__attribute__((address_space(3))) void*)&Bs[(w * 32 + 16) * 32], 16, 0, 0);
        }
        __syncthreads();

        f16x8 aF[4], bF[4];
#pragma unroll
        for (int i = 0; i < 4; ++i)
            aF[i] = *(const f16x8*)&As[(wr * 64 + i * 16 + frow) * 32 + koff];
#pragma unroll
        for (int j = 0; j < 4; ++j)
            bF[j] = *(const f16x8*)&Bs[(wc * 64 + j * 16 + frow) * 32 + koff];
#pragma unroll
        for (int i = 0; i < 4; ++i)
#pragma unroll
            for (int j = 0; j < 4; ++j)
                acc[i][j] = __builtin_amdgcn_mfma_f32_16x16x32_f16(
                    aF[i], bF[j], acc[i][j], 0, 0, 0);
    }

    float* Gb = G + (size_t)b * M * M;
    bool offd = (ti != tj);
    int r0 = (lane >> 4) * 4;
    int c0 = lane & 15;
#pragma unroll
    for (int i = 0; i < 4; ++i)
#pragma unroll
        for (int j = 0; j < 4; ++j)
#pragma unroll
            for (int r = 0; r < 4; ++r) {
                int gi = ti + wr * 64 + i * 16 + r0 + r;
                int gj = tj + wc * 64 + j * 16 + c0;
                float v = acc[i][j][r];
                atomicAdd(&Gb[(size_t)gi * M + gj], v);
                if (offd) atomicAdd(&Gb[(size_t)gj * M + gi], v);
            }
}

// ---------------------------------------------------------------------------
// K3: power iteration in M-space (G is tiny fp32).
// ---------------------------------------------------------------------------
__global__ __launch_bounds__(256) void k_power(const float* __restrict__ G,
                                               const float* __restrict__ u0,
                                               float* __restrict__ Lp) {
    int b = blockIdx.x;
    int m = threadIdx.x;
    __shared__ float su[M];
    __shared__ float red[4];
    su[m] = u0[b * M + m];
    __syncthreads();
    const float* Gb = G + (size_t)b * M * M;
    for (int it = 0; it < N_POWER; ++it) {
        float gm = 0.f;
        const float4* grow = (const float4*)(Gb + (size_t)m * M);
#pragma unroll 8
        for (int k = 0; k < M / 4; ++k) {
            float4 g = grow[k];
            gm += g.x * su[4 * k] + g.y * su[4 * k + 1] + g.z * su[4 * k + 2] +
                  g.w * su[4 * k + 3];
        }
        float part = su[m] * gm;
        for (int off = 32; off > 0; off >>= 1) part += __shfl_down(part, off, 64);
        if ((m & 63) == 0) red[m >> 6] = part;
        __syncthreads();
        float n = sqrtf(red[0] + red[1] + red[2] + red[3]);
        float inv = 1.f / (n + 1e-12f);
        su[m] = gm * inv;
        __syncthreads();
    }
    float part = su[m] * su[m];
    for (int off = 32; off > 0; off >>= 1) part += __shfl_down(part, off, 64);
    if ((m & 63) == 0) red[m >> 6] = part;
    __syncthreads();
    if (m == 0) {
        float L = (red[0] + red[1] + red[2] + red[3]) * (1.0f / 256.0f);
        Lp[b * 4 + 0] = L;
        Lp[b * 4 + 1] = 1.0f / (256.0f * L);
        Lp[b * 4 + 2] = ALPHA / L;
    }
}

// ---------------------------------------------------------------------------
// K4 (fused, self-reducing): ONE kernel per FISTA iteration.
// Each block: (1) issues its 16 tile loads (prefetch in flight),
// (2) takes a dynamic ticket; the first 64 started blocks each reduce one
// 32-wide slice of c = (sum_ch spart - y)/(M*L) from the PREVIOUS kernel's
// spart (kernel boundary = coherent), publish via agent-scope stores, bump
// done-counter (release). (3) all blocks spin on done==64 (thread 0,
// s_sleep), read c agent-coherently, then run pass1 / soft-threshold /
// pass2 exactly as before. Deadlock-free: tickets go only to blocks that
// are already executing (no dispatch-order assumption, G16).
// ---------------------------------------------------------------------------
__global__ __launch_bounds__(256) void k_fista(const __half* __restrict__ Aht,
                                               const float* __restrict__ y,
                                               const float* __restrict__ Lp,
                                               float* __restrict__ z,
                                               float* __restrict__ w,
                                               float* __restrict__ spart,
                                               float* __restrict__ c,
                                               int* __restrict__ flags,
                                               int it, float beta) {
    int cid = blockIdx.x;
    int b = cid >> 9;
    int chunk = cid & (NCH - 1);
    int d0 = chunk << 7;
    int t = threadIdx.x;
    int dj = t & 15;
    int mi = t >> 4;

    __shared__ float sc[M];
    __shared__ float gws[4][16][8];
    __shared__ float znS[128];
    __shared__ float sred[M];
    __shared__ float redp[8][32];
    __shared__ int s_ticket;

    // (1) prefetch the 256x128 tile into registers — in flight during spin
    const __half* Ap = Aht + (((size_t)b * NCH + chunk) * M + mi) * 128 + dj * 8;
    uint4 areg[16];
#pragma unroll
    for (int s = 0; s < 16; ++s)
        areg[s] = *(const uint4*)(Ap + (size_t)(s * 16) * 128);

    // (2) dynamic producer election
    if (t == 0) s_ticket = atomicAdd(&flags[2 * it], 1);
    __syncthreads();
    int ticket = s_ticket;

    if (ticket < 64) {
        int pb = ticket >> 3, mg = ticket & 7;
        int tm = t & 31, cg = t >> 5;
        int m = mg * 32 + tm;
        const float* sp = spart + (size_t)pb * NCH * M + m;
        float s = 0.f;
#pragma unroll 8
        for (int ch = cg; ch < NCH; ch += 8)
            s += sp[(size_t)ch * M];
        redp[cg][tm] = s;
        __syncthreads();
        if (t < 32) {
            float sv = 0.f;
#pragma unroll
            for (int g2 = 0; g2 < 8; ++g2) sv += redp[g2][t];
            int bm = pb * M + mg * 32 + t;
            float cv = (sv - y[bm]) * Lp[pb * 4 + 1];
            __hip_atomic_store(&c[bm], cv, __ATOMIC_RELAXED,
                               __HIP_MEMORY_SCOPE_AGENT);
        }
        __syncthreads();
        if (t == 0) {
            __threadfence();
            __hip_atomic_fetch_add(&flags[2 * it + 1], 1, __ATOMIC_RELEASE,
                                   __HIP_MEMORY_SCOPE_AGENT);
        }
    }

    // (3) wait for all 64 slices of c
    if (t == 0) {
        while (__hip_atomic_load(&flags[2 * it + 1], __ATOMIC_ACQUIRE,
                                 __HIP_MEMORY_SCOPE_AGENT) < 64)
            __builtin_amdgcn_s_sleep(2);
    }
    __syncthreads();
    sc[t] = __hip_atomic_load(&c[b * M + t], __ATOMIC_RELAXED,
                              __HIP_MEMORY_SCOPE_AGENT);
    __syncthreads();

    // pass 1: g = A^T c (per-thread 8 d's)
    float g[8] = {};
#pragma unroll
    for (int s = 0; s < 16; ++s) {
        float cm = sc[s * 16 + mi];
        const __half2* hp = (const __half2*)&areg[s];
        float2 f0 = __half22float2(hp[0]);
        float2 f1 = __half22float2(hp[1]);
        float2 f2 = __half22float2(hp[2]);
        float2 f3 = __half22float2(hp[3]);
        g[0] = fmaf(f0.x, cm, g[0]); g[1] = fmaf(f0.y, cm, g[1]);
        g[2] = fmaf(f1.x, cm, g[2]); g[3] = fmaf(f1.y, cm, g[3]);
        g[4] = fmaf(f2.x, cm, g[4]); g[5] = fmaf(f2.y, cm, g[5]);
        g[6] = fmaf(f3.x, cm, g[6]); g[7] = fmaf(f3.y, cm, g[7]);
    }
#pragma unroll
    for (int j = 0; j < 8; ++j) {
        g[j] += __shfl_xor(g[j], 16, 64);
        g[j] += __shfl_xor(g[j], 32, 64);
    }
    int wv = t >> 6;
    if ((t & 63) < 16) {
#pragma unroll
        for (int j = 0; j < 8; ++j) gws[wv][dj][j] = g[j];
    }
    __syncthreads();

    // soft-threshold update for this chunk's 128 d's
    if (t < 128) {
        int ldj = t >> 3, lj = t & 7;
        float gs = gws[0][ldj][lj] + gws[1][ldj][lj] +
                   gws[2][ldj][lj] + gws[3][ldj][lj];
        size_t zi = (size_t)b * D + d0 + t;
        float thr = Lp[b * 4 + 2];
        float zv = z[zi], wold = w[zi];
        float cand = zv - gs;
        float a1 = fabsf(cand) - thr;
        float wn = a1 > 0.f ? copysignf(a1, cand) : 0.f;
        float znv = wn + beta * (wn - wold);
        w[zi] = wn;
        z[zi] = znv;
        znS[t] = znv;
    }
    __syncthreads();

    // pass 2: partial A z_new for this chunk
    float zr[8];
    {
        float4 z0 = *(const float4*)&znS[dj * 8];
        float4 z1 = *(const float4*)&znS[dj * 8 + 4];
        zr[0] = z0.x; zr[1] = z0.y; zr[2] = z0.z; zr[3] = z0.w;
        zr[4] = z1.x; zr[5] = z1.y; zr[6] = z1.z; zr[7] = z1.w;
    }
#pragma unroll
    for (int s = 0; s < 16; ++s) {
        const __half2* hp = (const __half2*)&areg[s];
        float2 f0 = __half22float2(hp[0]);
        float2 f1 = __half22float2(hp[1]);
        float2 f2 = __half22float2(hp[2]);
        float2 f3 = __half22float2(hp[3]);
        float p = f0.x * zr[0] + f0.y * zr[1] + f1.x * zr[2] + f1.y * zr[3] +
                  f2.x * zr[4] + f2.y * zr[5] + f3.x * zr[6] + f3.y * zr[7];
        p += __shfl_xor(p, 1, 64);
        p += __shfl_xor(p, 2, 64);
        p += __shfl_xor(p, 4, 64);
        p += __shfl_xor(p, 8, 64);
        if (dj == 0) sred[s * 16 + mi] = p;
    }
    __syncthreads();
    spart[((size_t)b * NCH + chunk) * M + t] = sred[t];
}

// ---------------------------------------------------------------------------
extern "C" void kernel_launch(void* const* d_in, const int* in_sizes, int n_in,
                              void* d_out, int out_size, void* d_ws, size_t ws_size,
                              hipStream_t stream) {
    (void)in_sizes; (void)n_in; (void)out_size; (void)ws_size;
    const float* x = (const float*)d_in[0];        // [B, D]
    const float* A = (const float*)d_in[1];        // [B, M, D]
    float* w = (float*)d_out;                      // [B, D]

    // workspace layout: Aht (fp16 tile-major, 256 MiB) first, fp32 after
    __half* Aht = (__half*)d_ws;
    float* ws = (float*)((char*)d_ws + (size_t)B * M * D * sizeof(__half));
    float* y  = ws;                 // 2048
    float* u  = ws + 2048;          // 2048
    float* Lp = ws + 4096;          // 32
    float* c  = ws + 4128;          // 2048
    float* z  = ws + 8192;          // 524288 floats (2 MiB)
    float* G  = ws + 8192 + 524288; // 65536 floats (overlapped by spart)
    float* spart = G;               // B*NCH*M = 1048576 floats (4 MiB)
    float* ypart = spart + (size_t)B * NCH * M;   // 4 MiB
    float* upart = ypart + (size_t)B * NCH * M;   // 4 MiB
    int*   flags = (int*)(upart + (size_t)B * NCH * M);  // 2*N_ITERS ints

    hipMemsetAsync(G, 0, (size_t)B * M * M * sizeof(float), stream);
    hipMemsetAsync(z, 0, (size_t)B * D * sizeof(float), stream);
    hipMemsetAsync(w, 0, (size_t)B * D * sizeof(float), stream);
    hipMemsetAsync(flags, 0, 2 * N_ITERS * sizeof(int), stream);

    k_conv<<<16384, 256, 0, stream>>>(A, Aht);
    k_ypart<<<B * NCH, 256, 0, stream>>>(Aht, x, ypart, upart);
    k_yred<<<64, 256, 0, stream>>>(ypart, upart, y, u);
    k_gram_mfma<<<8 * 3 * 32, 256, 0, stream>>>(Aht, G);
    k_power<<<B, 256, 0, stream>>>(G, u, Lp);

    // spart must be zero before iteration 0 (=> s = A*0 = 0); stream-ordered
    // after k_power since it overlaps G.
    hipMemsetAsync(spart, 0, (size_t)B * NCH * M * sizeof(float), stream);

    double t = 1.0;
    for (int k = 0; k < N_ITERS; ++k) {
        double tn = 0.5 * (1.0 + sqrt(1.0 + 4.0 * t * t));
        float beta = (float)((t - 1.0) / tn);
        k_fista<<<B * NCH, 256, 0, stream>>>(Aht, y, Lp, z, w, spart, c,
                                             flags, k, beta);
        t = tn;
    }
}

// Round 5
// 3964.681 us; speedup vs baseline: 5.3649x; 5.3649x over previous
//
#include <hip/hip_runtime.h>
#include <hip/hip_fp16.h>
#include <math.h>

#define B 8
#define M 256
#define D 65536
#define NCH 512   // D / 128 column-chunks

static constexpr float ALPHA = 0.5f;
static constexpr int N_ITERS = 50;
static constexpr int N_POWER = 10;

typedef _Float16 f16x8 __attribute__((ext_vector_type(8)));
typedef float f32x4 __attribute__((ext_vector_type(4)));

// ---------------------------------------------------------------------------
// Tile-major fp16 layout: Aht[b][ch][m][dlo], ch = d>>7, dlo = d&127.
// ---------------------------------------------------------------------------

// K0 (fused): convert A fp32 -> fp16 tile-major AND emit per-(b,ch,m)
// partials of y = Ah.x and rowsum(Ah). The converted halves are already in
// registers; the extra dot/rowsum is ~5 us of VALU + L2-resident x reads,
// hidden under the 1.5 GiB memory floor. Eliminates the separate k_ypart
// pass (512 MiB re-read of Aht).
__global__ __launch_bounds__(256) void k_conv_y(const float* __restrict__ A,
                                                const float* __restrict__ x,
                                                __half* __restrict__ Aht,
                                                float* __restrict__ ypart,
                                                float* __restrict__ upart) {
    const size_t n8 = (size_t)B * M * D / 8;  // 16,777,216 output uint4s
    size_t stride = (size_t)gridDim.x * 256;
    for (size_t i = (size_t)blockIdx.x * 256 + threadIdx.x; i < n8; i += stride) {
        size_t dlo8 = i & 15;
        size_t m  = (i >> 4) & (M - 1);
        size_t ch = (i >> 12) & (NCH - 1);
        size_t b  = i >> 21;
        size_t in8 = (b << 21) | (m << 13) | (ch << 4) | dlo8;
        float4 f0 = ((const float4*)A)[2 * in8];
        float4 f1 = ((const float4*)A)[2 * in8 + 1];
        union { uint4 u; __half2 h[4]; } o;
        o.h[0] = __floats2half2_rn(f0.x, f0.y);
        o.h[1] = __floats2half2_rn(f0.z, f0.w);
        o.h[2] = __floats2half2_rn(f1.x, f1.y);
        o.h[3] = __floats2half2_rn(f1.z, f1.w);
        ((uint4*)Aht)[i] = o.u;

        // y/u partials from the CONVERTED halves (same quantization as all
        // later math). x slice: 8 consecutive fp32 (x is 2 MB -> L2-hit).
        const float4* xp =
            (const float4*)(x + ((b << 16) | (ch << 7) | (dlo8 << 3)));
        float4 x0 = xp[0], x1 = xp[1];
        float2 g0 = __half22float2(o.h[0]);
        float2 g1 = __half22float2(o.h[1]);
        float2 g2 = __half22float2(o.h[2]);
        float2 g3 = __half22float2(o.h[3]);
        float p = g0.x * x0.x + g0.y * x0.y + g1.x * x0.z + g1.y * x0.w +
                  g2.x * x1.x + g2.y * x1.y + g3.x * x1.z + g3.y * x1.w;
        float q = g0.x + g0.y + g1.x + g1.y + g2.x + g2.y + g3.x + g3.y;
        // reduce across the 16-lane dlo8 group (aligned within the wave)
        p += __shfl_xor(p, 1, 64); q += __shfl_xor(q, 1, 64);
        p += __shfl_xor(p, 2, 64); q += __shfl_xor(q, 2, 64);
        p += __shfl_xor(p, 4, 64); q += __shfl_xor(q, 4, 64);
        p += __shfl_xor(p, 8, 64); q += __shfl_xor(q, 8, 64);
        if (dlo8 == 0) {
            ypart[i >> 4] = p;   // index == (b*NCH+ch)*M + m
            upart[i >> 4] = q;
        }
    }
}

// K1b: y[b,m] = sum_ch ypart; u[b,m] = sum_ch upart / 256
__global__ __launch_bounds__(256) void k_yred(const float* __restrict__ ypart,
                                              const float* __restrict__ upart,
                                              float* __restrict__ y,
                                              float* __restrict__ u) {
    int blk = blockIdx.x;          // 64 = B * 8
    int b = blk >> 3;
    int mg = blk & 7;
    int t = threadIdx.x;
    int tm = t & 31;
    int cg = t >> 5;
    int m = mg * 32 + tm;
    const float* yp = ypart + (size_t)b * NCH * M + m;
    const float* up = upart + (size_t)b * NCH * M + m;
    float sy = 0.f, su = 0.f;
#pragma unroll 8
    for (int ch = cg; ch < NCH; ch += 8) {
        sy += yp[(size_t)ch * M];
        su += up[(size_t)ch * M];
    }
    __shared__ float redY[8][32], redU[8][32];
    redY[cg][tm] = sy; redU[cg][tm] = su;
    __syncthreads();
    if (t < 32) {
        float vy = 0.f, vu = 0.f;
#pragma unroll
        for (int g = 0; g < 8; ++g) { vy += redY[g][t]; vu += redU[g][t]; }
        int bm = b * M + mg * 32 + t;
        y[bm] = vy;
        u[bm] = vu * 0.00390625f;
    }
}

// ---------------------------------------------------------------------------
// K2 (MFMA): Gram G[b] = Ah[b] * Ah[b]^T using v_mfma_f32_16x16x32_f16.
// ---------------------------------------------------------------------------
__global__ __launch_bounds__(256) void k_gram_mfma(const __half* __restrict__ Aht,
                                                   float* __restrict__ G) {
    int bx = blockIdx.x;
    int ch2 = bx & 31;             // 32 K-chunks of 2048
    int p  = (bx >> 5) % 3;        // pair: (0,0) (0,128) (128,128)
    int b  = bx / 96;
    const int PI[3] = {0, 0, 128};
    const int PJ[3] = {0, 128, 128};
    int ti = PI[p], tj = PJ[p];
    int k0 = ch2 * 2048;

    __shared__ __half As[128 * 32];
    __shared__ __half Bs[128 * 32];

    int t = threadIdx.x;
    int w = t >> 6, lane = t & 63;
    int wr = w >> 1, wc = w & 1;

    int srow = w * 32 + (lane >> 2);
    int scol = (lane & 3) * 8;

    f32x4 acc[4][4];
#pragma unroll
    for (int i = 0; i < 4; ++i)
#pragma unroll
        for (int j = 0; j < 4; ++j)
            acc[i][j] = (f32x4){0.f, 0.f, 0.f, 0.f};

    int frow = lane & 15;
    int koff = (lane >> 4) * 8;

    const size_t bbase = (size_t)b * NCH;
    for (int ks = 0; ks < 2048; ks += 32) {
        int d = k0 + ks;
        size_t chb = bbase + (d >> 7);
        int dlo = d & 127;
        __syncthreads();
        {
            const __half* ga0 = Aht + (chb * M + (ti + srow)) * 128 + dlo + scol;
            const __half* ga1 = ga0 + 16 * 128;
            const __half* gb0 = Aht + (chb * M + (tj + srow)) * 128 + dlo + scol;
            const __half* gb1 = gb0 + 16 * 128;
            __builtin_amdgcn_global_load_lds(
                (const __attribute__((address_space(1))) void*)ga0,
                (__attribute__((address_space(3))) void*)&As[(w * 32) * 32], 16, 0, 0);
            __builtin_amdgcn_global_load_lds(
                (const __attribute__((address_space(1))) void*)ga1,
                (__attribute__((address_space(3))) void*)&As[(w * 32 + 16) * 32], 16, 0, 0);
            __builtin_amdgcn_global_load_lds(
                (const __attribute__((address_space(1))) void*)gb0,
                (__attribute__((address_space(3))) void*)&Bs[(w * 32) * 32], 16, 0, 0);
            __builtin_amdgcn_global_load_lds(
                (const __attribute__((address_space(1))) void*)gb1,
                (__attribute__((address_space(3))) void*)&Bs[(w * 32 + 16) * 32], 16, 0, 0);
        }
        __syncthreads();

        f16x8 aF[4], bF[4];
#pragma unroll
        for (int i = 0; i < 4; ++i)
            aF[i] = *(const f16x8*)&As[(wr * 64 + i * 16 + frow) * 32 + koff];
#pragma unroll
        for (int j = 0; j < 4; ++j)
            bF[j] = *(const f16x8*)&Bs[(wc * 64 + j * 16 + frow) * 32 + koff];
#pragma unroll
        for (int i = 0; i < 4; ++i)
#pragma unroll
            for (int j = 0; j < 4; ++j)
                acc[i][j] = __builtin_amdgcn_mfma_f32_16x16x32_f16(
                    aF[i], bF[j], acc[i][j], 0, 0, 0);
    }

    float* Gb = G + (size_t)b * M * M;
    bool offd = (ti != tj);
    int r0 = (lane >> 4) * 4;
    int c0 = lane & 15;
#pragma unroll
    for (int i = 0; i < 4; ++i)
#pragma unroll
        for (int j = 0; j < 4; ++j)
#pragma unroll
            for (int r = 0; r < 4; ++r) {
                int gi = ti + wr * 64 + i * 16 + r0 + r;
                int gj = tj + wc * 64 + j * 16 + c0;
                float v = acc[i][j][r];
                atomicAdd(&Gb[(size_t)gi * M + gj], v);
                if (offd) atomicAdd(&Gb[(size_t)gj * M + gi], v);
            }
}

// ---------------------------------------------------------------------------
// K3: power iteration in M-space (G is tiny fp32).
// ---------------------------------------------------------------------------
__global__ __launch_bounds__(256) void k_power(const float* __restrict__ G,
                                               const float* __restrict__ u0,
                                               float* __restrict__ Lp) {
    int b = blockIdx.x;
    int m = threadIdx.x;
    __shared__ float su[M];
    __shared__ float red[4];
    su[m] = u0[b * M + m];
    __syncthreads();
    const float* Gb = G + (size_t)b * M * M;
    for (int it = 0; it < N_POWER; ++it) {
        float gm = 0.f;
        const float4* grow = (const float4*)(Gb + (size_t)m * M);
#pragma unroll 8
        for (int k = 0; k < M / 4; ++k) {
            float4 g = grow[k];
            gm += g.x * su[4 * k] + g.y * su[4 * k + 1] + g.z * su[4 * k + 2] +
                  g.w * su[4 * k + 3];
        }
        float part = su[m] * gm;
        for (int off = 32; off > 0; off >>= 1) part += __shfl_down(part, off, 64);
        if ((m & 63) == 0) red[m >> 6] = part;
        __syncthreads();
        float n = sqrtf(red[0] + red[1] + red[2] + red[3]);
        float inv = 1.f / (n + 1e-12f);
        su[m] = gm * inv;
        __syncthreads();
    }
    float part = su[m] * su[m];
    for (int off = 32; off > 0; off >>= 1) part += __shfl_down(part, off, 64);
    if ((m & 63) == 0) red[m >> 6] = part;
    __syncthreads();
    if (m == 0) {
        float L = (red[0] + red[1] + red[2] + red[3]) * (1.0f / 256.0f);
        Lp[b * 4 + 0] = L;
        Lp[b * 4 + 1] = 1.0f / (256.0f * L);
        Lp[b * 4 + 2] = ALPHA / L;
    }
}

// ---------------------------------------------------------------------------
// K4a: c[b,m] = (sum_chunk spart[b][chunk][m] - y[b,m]) / (M*L_b)
// ---------------------------------------------------------------------------
__global__ __launch_bounds__(256) void k_cstep(const float* __restrict__ spart,
                                               const float* __restrict__ y,
                                               const float* __restrict__ Lp,
                                               float* __restrict__ c) {
    int blk = blockIdx.x;
    int b = blk >> 3;
    int mg = blk & 7;
    int t = threadIdx.x;
    int tm = t & 31;
    int cg = t >> 5;               // 0..7
    int m = mg * 32 + tm;
    const float* sp = spart + (size_t)b * NCH * M + m;
    float s = 0.f;
#pragma unroll 8
    for (int ch = cg; ch < NCH; ch += 8)
        s += sp[(size_t)ch * M];
    __shared__ float red[8][32];
    red[cg][tm] = s;
    __syncthreads();
    if (t < 32) {
        float sv = red[0][t] + red[1][t] + red[2][t] + red[3][t] +
                   red[4][t] + red[5][t] + red[6][t] + red[7][t];
        int bm = b * M + mg * 32 + t;
        c[bm] = (sv - y[bm]) * Lp[b * 4 + 1];
    }
}

// ---------------------------------------------------------------------------
// K4b (fused): single pass over A per iteration; register-resident tile used
// for both A^T c and the partial A z_new. Each block processes TWO 128-col
// chunks (c-vector LDS load + launch/tail fixed costs amortized 2x; VGPR
// footprint unchanged since areg is reused per chunk).
// ---------------------------------------------------------------------------
__global__ __launch_bounds__(256) void k_fista(const __half* __restrict__ Aht,
                                               const float* __restrict__ cc,
                                               const float* __restrict__ Lp,
                                               float* __restrict__ z,
                                               float* __restrict__ w,
                                               float* __restrict__ spart,
                                               float beta) {
    int cid = blockIdx.x;          // 2048 blocks
    int b = cid >> 8;
    int pair = cid & 255;
    int t = threadIdx.x;
    int dj = t & 15;
    int mi = t >> 4;

    __shared__ float sc[M];        // c vector (shared by both chunks)
    __shared__ float gws[4][16][8];
    __shared__ float znS[128];
    __shared__ float sred[M];

    sc[t] = cc[b * M + t];
    __syncthreads();
    float thr = Lp[b * 4 + 2];

    for (int half = 0; half < 2; ++half) {
        int chunk = pair * 2 + half;
        int d0 = chunk << 7;

        const __half* Ap =
            Aht + (((size_t)b * NCH + chunk) * M + mi) * 128 + dj * 8;
        uint4 areg[16];
        float g[8] = {};
#pragma unroll
        for (int s = 0; s < 16; ++s) {
            areg[s] = *(const uint4*)(Ap + (size_t)(s * 16) * 128);
            float cm = sc[s * 16 + mi];
            const __half2* hp = (const __half2*)&areg[s];
            float2 f0 = __half22float2(hp[0]);
            float2 f1 = __half22float2(hp[1]);
            float2 f2 = __half22float2(hp[2]);
            float2 f3 = __half22float2(hp[3]);
            g[0] = fmaf(f0.x, cm, g[0]); g[1] = fmaf(f0.y, cm, g[1]);
            g[2] = fmaf(f1.x, cm, g[2]); g[3] = fmaf(f1.y, cm, g[3]);
            g[4] = fmaf(f2.x, cm, g[4]); g[5] = fmaf(f2.y, cm, g[5]);
            g[6] = fmaf(f3.x, cm, g[6]); g[7] = fmaf(f3.y, cm, g[7]);
        }
#pragma unroll
        for (int j = 0; j < 8; ++j) {
            g[j] += __shfl_xor(g[j], 16, 64);
            g[j] += __shfl_xor(g[j], 32, 64);
        }
        int wv = t >> 6;
        if ((t & 63) < 16) {
#pragma unroll
            for (int j = 0; j < 8; ++j) gws[wv][dj][j] = g[j];
        }
        __syncthreads();

        // soft-threshold update for this chunk's 128 d's
        if (t < 128) {
            int ldj = t >> 3, lj = t & 7;
            float gs = gws[0][ldj][lj] + gws[1][ldj][lj] +
                       gws[2][ldj][lj] + gws[3][ldj][lj];
            size_t zi = (size_t)b * D + d0 + t;
            float zv = z[zi], wold = w[zi];
            float cand = zv - gs;
            float a1 = fabsf(cand) - thr;
            float wn = a1 > 0.f ? copysignf(a1, cand) : 0.f;
            float znv = wn + beta * (wn - wold);
            w[zi] = wn;
            z[zi] = znv;
            znS[t] = znv;
        }
        __syncthreads();

        // pass 2: partial A z_new for this chunk
        float zr[8];
        {
            float4 z0 = *(const float4*)&znS[dj * 8];
            float4 z1 = *(const float4*)&znS[dj * 8 + 4];
            zr[0] = z0.x; zr[1] = z0.y; zr[2] = z0.z; zr[3] = z0.w;
            zr[4] = z1.x; zr[5] = z1.y; zr[6] = z1.z; zr[7] = z1.w;
        }
#pragma unroll
        for (int s = 0; s < 16; ++s) {
            const __half2* hp = (const __half2*)&areg[s];
            float2 f0 = __half22float2(hp[0]);
            float2 f1 = __half22float2(hp[1]);
            float2 f2 = __half22float2(hp[2]);
            float2 f3 = __half22float2(hp[3]);
            float p = f0.x * zr[0] + f0.y * zr[1] + f1.x * zr[2] +
                      f1.y * zr[3] + f2.x * zr[4] + f2.y * zr[5] +
                      f3.x * zr[6] + f3.y * zr[7];
            p += __shfl_xor(p, 1, 64);
            p += __shfl_xor(p, 2, 64);
            p += __shfl_xor(p, 4, 64);
            p += __shfl_xor(p, 8, 64);
            if (dj == 0) sred[s * 16 + mi] = p;
        }
        __syncthreads();
        spart[((size_t)b * NCH + chunk) * M + t] = sred[t];
        // next half's gws/znS/sred writes are each >=2 barriers after their
        // last read above -> no extra barrier needed here
    }
}

// ---------------------------------------------------------------------------
extern "C" void kernel_launch(void* const* d_in, const int* in_sizes, int n_in,
                              void* d_out, int out_size, void* d_ws, size_t ws_size,
                              hipStream_t stream) {
    (void)in_sizes; (void)n_in; (void)out_size; (void)ws_size;
    const float* x = (const float*)d_in[0];        // [B, D]
    const float* A = (const float*)d_in[1];        // [B, M, D]
    float* w = (float*)d_out;                      // [B, D]

    // workspace layout: Aht (fp16 tile-major, 256 MiB) first, fp32 after
    __half* Aht = (__half*)d_ws;
    float* ws = (float*)((char*)d_ws + (size_t)B * M * D * sizeof(__half));
    float* y  = ws;                 // 2048
    float* u  = ws + 2048;          // 2048
    float* Lp = ws + 4096;          // 32
    float* c  = ws + 4128;          // 2048
    float* z  = ws + 8192;          // 524288 floats (2 MiB)
    float* G  = ws + 8192 + 524288; // 65536 floats (overlapped by spart)
    float* spart = G;               // B*NCH*M = 1048576 floats (4 MiB)
    float* ypart = spart + (size_t)B * NCH * M;   // 4 MiB
    float* upart = ypart + (size_t)B * NCH * M;   // 4 MiB

    hipMemsetAsync(G, 0, (size_t)B * M * M * sizeof(float), stream);
    hipMemsetAsync(z, 0, (size_t)B * D * sizeof(float), stream);
    hipMemsetAsync(w, 0, (size_t)B * D * sizeof(float), stream);

    k_conv_y<<<16384, 256, 0, stream>>>(A, x, Aht, ypart, upart);
    k_yred<<<64, 256, 0, stream>>>(ypart, upart, y, u);
    k_gram_mfma<<<8 * 3 * 32, 256, 0, stream>>>(Aht, G);
    k_power<<<B, 256, 0, stream>>>(G, u, Lp);

    // spart must be zero before iteration 0 (=> s = A*0 = 0); stream-ordered
    // after k_power since it overlaps G.
    hipMemsetAsync(spart, 0, (size_t)B * NCH * M * sizeof(float), stream);

    double t = 1.0;
    for (int k = 0; k < N_ITERS; ++k) {
        double tn = 0.5 * (1.0 + sqrt(1.0 + 4.0 * t * t));
        float beta = (float)((t - 1.0) / tn);
        k_cstep<<<64, 256, 0, stream>>>(spart, y, Lp, c);
        k_fista<<<2048, 256, 0, stream>>>(Aht, c, Lp, z, w, spart, beta);
        t = tn;
    }
}